// Round 2
// baseline (278.486 us; speedup 1.0000x reference)
//
#include <hip/hip_runtime.h>

typedef __bf16 bf16;
typedef bf16 bf16x8 __attribute__((ext_vector_type(8)));
typedef bf16 bf16x4 __attribute__((ext_vector_type(4)));
typedef bf16 bf16x2 __attribute__((ext_vector_type(2)));
typedef float f32x4 __attribute__((ext_vector_type(4)));
typedef float f32x16 __attribute__((ext_vector_type(16)));
typedef unsigned int u32;
typedef u32 u32x4 __attribute__((ext_vector_type(4)));
typedef int i32x2 __attribute__((ext_vector_type(2)));

constexpr int Bb = 4, Ss = 2048, Dd = 1024, NH = 16, HD = 64;
constexpr int BS = Bb * Ss;          // 8192
constexpr float CSC = 0.18033688011112042f;  // (1/sqrt(64)) * log2(e), folded into Wq

__device__ __forceinline__ int sw(int row, int col) {
  return (row << 6) + (col ^ ((row & 7) << 3));
}
__device__ __forceinline__ int sw128(int row, int col) {
  return (row << 7) + (col ^ ((row & 7) << 3));
}

__device__ __forceinline__ void g2l16(const bf16* g, bf16* l) {
  __builtin_amdgcn_global_load_lds(
      (const __attribute__((address_space(1))) void*)g,
      (__attribute__((address_space(3))) void*)l, 16, 0, 0);
}

__device__ __forceinline__ u32 pkbf(float a, float b) {
  bf16x2 v = {(bf16)a, (bf16)b};
  return __builtin_bit_cast(u32, v);
}

// ---------------- prep: x cvt + weight transposes + bias ----------------
__global__ void prep(const float* __restrict__ x, bf16* __restrict__ xb,
                     const float* __restrict__ Wq, const float* __restrict__ Wk,
                     const float* __restrict__ Wv, const float* __restrict__ Wo,
                     const float* __restrict__ bq, const float* __restrict__ bk,
                     const float* __restrict__ bv,
                     bf16* __restrict__ WT_all, bf16* __restrict__ WoT,
                     float* __restrict__ bias_all) {
  __shared__ bf16 Ts[64 * 72];
  const int t = threadIdx.x;
  if (blockIdx.y == 0) {           // x: f32 -> bf16 (8192 blocks)
    int o = (blockIdx.x * 256 + t) * 4;
    f32x4 v = *(const f32x4*)&x[o];
    bf16x4 r = {(bf16)v[0], (bf16)v[1], (bf16)v[2], (bf16)v[3]};
    *(bf16x4*)&xb[o] = r;
    return;
  }
  if (blockIdx.x > 1024) return;
  if (blockIdx.x == 1024) {
    for (int j = t; j < 3072; j += 256) {
      int s2 = j >> 10;
      const float* bb = (s2 == 0) ? bq : (s2 == 1) ? bk : bv;
      bias_all[j] = bb[j & 1023] * (s2 == 0 ? CSC : 1.0f);
    }
    return;
  }
  const int sel = blockIdx.x >> 8, bx = blockIdx.x & 255;
  if (sel < 3) {
    const float* W = (sel == 0) ? Wq : (sel == 1) ? Wk : Wv;
    float scale = (sel == 0) ? CSC : 1.0f;
    int head = bx >> 4, dt = bx & 15;
    const float* src = W + head * 65536 + dt * 64 * 64;   // [64 d][64 h]
#pragma unroll
    for (int i = 0; i < 4; ++i) {
      int idx = i * 256 + t;
      int dr = idx >> 4, hc = (idx & 15) * 4;
      f32x4 v = *(const f32x4*)&src[dr * 64 + hc];
#pragma unroll
      for (int k = 0; k < 4; ++k) Ts[(hc + k) * 72 + dr] = (bf16)(v[k] * scale);
    }
    __syncthreads();
    bf16* dst = WT_all + (size_t)sel * 1048576 + (size_t)(head * 64) * 1024 + dt * 64;
#pragma unroll
    for (int i = 0; i < 2; ++i) {
      int idx = i * 256 + t;
      int hr = idx >> 3, ch = (idx & 7) * 8;
      *(bf16x8*)&dst[(size_t)hr * 1024 + ch] = *(const bf16x8*)&Ts[hr * 72 + ch];
    }
  } else {
    int ct = bx >> 4, dt = bx & 15;
    const float* src = Wo + (size_t)(ct * 64) * 1024 + dt * 64;
#pragma unroll
    for (int i = 0; i < 4; ++i) {
      int idx = i * 256 + t;
      int cr = idx >> 4, dc = (idx & 15) * 4;
      f32x4 v = *(const f32x4*)&src[(size_t)cr * 1024 + dc];
#pragma unroll
      for (int k = 0; k < 4; ++k) Ts[(dc + k) * 72 + cr] = (bf16)v[k];
    }
    __syncthreads();
    bf16* dst = WoT + (size_t)(dt * 64) * 1024 + ct * 64;
#pragma unroll
    for (int i = 0; i < 2; ++i) {
      int idx = i * 256 + t;
      int dr = idx >> 3, ch = (idx & 7) * 8;
      *(bf16x8*)&dst[(size_t)dr * 1024 + ch] = *(const bf16x8*)&Ts[dr * 72 + ch];
    }
  }
}

// ---------------- shared 128x128 K=1024 MFMA core ----------------
__device__ __forceinline__ void gemm_core(const bf16* __restrict__ A,
                                          const bf16* __restrict__ BT,
                                          int m0, int n0, bf16* As, bf16* Bs,
                                          f32x4 (&acc)[4][4]) {
  const int t = threadIdx.x;
  const int l = t & 63, q = l >> 4, lm = l & 15;
  const int w = t >> 6, wm = w & 1, wn = w >> 1;
  int ro[4], co[4];
#pragma unroll
  for (int i = 0; i < 4; ++i) {
    int o = i * 256 + t;
    ro[i] = o >> 3;
    co[i] = ((o & 7) ^ ((o >> 3) & 7)) << 3;
  }
  const int lbase = (t & 192) * 8;
  for (int k0 = 0; k0 < 1024; k0 += 64) {
    __syncthreads();
#pragma unroll
    for (int i = 0; i < 4; ++i)
      g2l16(&A[(size_t)(m0 + ro[i]) * 1024 + k0 + co[i]], &As[i * 2048 + lbase]);
#pragma unroll
    for (int i = 0; i < 4; ++i)
      g2l16(&BT[(size_t)(n0 + ro[i]) * 1024 + k0 + co[i]], &Bs[i * 2048 + lbase]);
    __syncthreads();
#pragma unroll
    for (int kh = 0; kh < 2; ++kh) {
      bf16x8 a[4], b[4];
#pragma unroll
      for (int i = 0; i < 4; ++i)
        a[i] = *(const bf16x8*)&As[sw(wm * 64 + i * 16 + lm, kh * 32 + q * 8)];
#pragma unroll
      for (int i = 0; i < 4; ++i)
        b[i] = *(const bf16x8*)&Bs[sw(wn * 64 + i * 16 + lm, kh * 32 + q * 8)];
#pragma unroll
      for (int mt = 0; mt < 4; ++mt)
#pragma unroll
        for (int nt = 0; nt < 4; ++nt)
          acc[mt][nt] = __builtin_amdgcn_mfma_f32_16x16x32_bf16(a[mt], b[nt], acc[mt][nt], 0, 0, 0);
    }
  }
}

// ---------------- fused QK + V GEMM (1536 blocks) ----------------
__global__ __launch_bounds__(256) void gemm_qkv(const bf16* __restrict__ xb,
                                                const bf16* __restrict__ WT,
                                                const float* __restrict__ bias_all,
                                                bf16* __restrict__ QKb,
                                                bf16* __restrict__ VTb) {
  __shared__ __align__(16) bf16 SMEM[2 * 128 * 64];
  bf16* As = SMEM;
  bf16* Bs = SMEM + 128 * 64;
  const int bid = blockIdx.x;
  const int t = threadIdx.x;
  const int l = t & 63, q = l >> 4, lm = l & 15;
  const int w = t >> 6, wm = w & 1, wn = w >> 1;
  const bool vmode = bid >= 1024;
  int m0, n0;
  const bf16 *A, *BT;
  if (!vmode) {
    int xcd = bid & 7, idx = bid >> 3;
    m0 = (idx >> 1) * 128;
    n0 = (xcd * 2 + (idx & 1)) * 128;
    A = xb; BT = WT;
  } else {
    int b2 = bid - 1024;
    int xcd = b2 & 7, idx = b2 >> 3;
    m0 = (idx >> 3) * 128;
    n0 = (xcd * 8 + (idx & 7)) * 128;
    A = WT + (size_t)2048 * 1024; BT = xb;
  }
  f32x4 acc[4][4] = {};
  gemm_core(A, BT, m0, n0, As, Bs, acc);
  if (vmode) {
    // stage C-tile (m=nh 128, n=s 128) in LDS, then write coalesced VT rows
    __syncthreads();
#pragma unroll
    for (int nt = 0; nt < 4; ++nt) {
      int sl = wn * 64 + nt * 16 + lm;
#pragma unroll
      for (int mt = 0; mt < 4; ++mt) {
        int ml = wm * 64 + mt * 16 + q * 4;
#pragma unroll
        for (int r = 0; r < 4; ++r)
          SMEM[sw128(ml + r, sl)] = (bf16)(acc[mt][nt][r] + bias_all[2048 + m0 + ml + r]);
      }
    }
    __syncthreads();
    int hh = t >> 1, half = (t & 1) * 64;
    int m = m0 + hh;
    size_t gb = (size_t)((n0 >> 11) * 16 + (m >> 6)) * 131072 +
                (size_t)(m & 63) * 2048 + (n0 & 2047) + half;
#pragma unroll
    for (int k = 0; k < 8; ++k)
      *(bf16x8*)&VTb[gb + k * 8] = *(const bf16x8*)&SMEM[sw128(hh, half + k * 8)];
  } else {
#pragma unroll
    for (int nt = 0; nt < 4; ++nt) {
      int col = n0 + wn * 64 + nt * 16 + lm;
      float bb = bias_all[col];
#pragma unroll
      for (int mt = 0; mt < 4; ++mt) {
        int row = m0 + wm * 64 + mt * 16 + q * 4;
#pragma unroll
        for (int r = 0; r < 4; ++r)
          QKb[(size_t)(row + r) * 2048 + col] = (bf16)(acc[mt][nt][r] + bb);
      }
    }
  }
}

// ---------------- out-proj GEMM (512 blocks, f32 out) ----------------
__global__ __launch_bounds__(256) void gemm_out(const bf16* __restrict__ after,
                                                const bf16* __restrict__ WoT,
                                                const float* __restrict__ bo,
                                                float* __restrict__ out) {
  __shared__ __align__(16) bf16 SMEM[2 * 128 * 64];
  const int bid = blockIdx.x;
  const int t = threadIdx.x;
  const int l = t & 63, q = l >> 4, lm = l & 15;
  const int w = t >> 6, wm = w & 1, wn = w >> 1;
  const int xcd = bid & 7, idx = bid >> 3;
  const int n0 = xcd * 128, m0 = idx * 128;
  f32x4 acc[4][4] = {};
  gemm_core(after, WoT, m0, n0, SMEM, SMEM + 128 * 64, acc);
#pragma unroll
  for (int nt = 0; nt < 4; ++nt) {
    int col = n0 + wn * 64 + nt * 16 + lm;
    float bb = bo[col];
#pragma unroll
    for (int mt = 0; mt < 4; ++mt) {
      int row = m0 + wm * 64 + mt * 16 + q * 4;
#pragma unroll
      for (int r = 0; r < 4; ++r)
        out[(size_t)(row + r) * 1024 + col] = acc[mt][nt][r] + bb;
    }
  }
}

// ---------------- flash attention: 32x32 MFMA, 64 Q-rows/wave ----------------
// 512 blocks; 4 waves x 64 Q-rows. K/V staged 4-deep in LDS (64KB), prefetch
// 3 tiles ahead; per-iter raw s_barrier + counted s_waitcnt vmcnt(8) -- the
// T3/T4 counted-vmcnt pipeline (never drain to 0 in the main loop).
__global__ __launch_bounds__(256, 2) void attn(const bf16* __restrict__ QK,
                                               const bf16* __restrict__ VT,
                                               bf16* __restrict__ after) {
  // 64KB: K stages [4][4096] at 0, V stages [4][4096] at 16384 (elements).
  __shared__ __align__(16) bf16 SMEM[32768];
  const int t = threadIdx.x;
  const int l = t & 63, w = t >> 6;
  const int lh = l & 31, H = l >> 5;          // half-wave id
  const int f = blockIdx.x;
  const int bn = (f & 7) | ((f >> 6) << 3);   // XCD keeps one bn-group's K/V in L2
  const int s0 = ((f >> 3) & 7) * 256;
  const int b = bn >> 4, n = bn & 15;
  const bf16* Qb = QK + (size_t)(b * 2048) * 2048 + n * 64;
  const bf16* Kb = Qb + 1024;
  const bf16* Vtb = VT + (size_t)bn * 131072;
  const int rr = t >> 3;                       // row-in-32 per staging iter
  const int co0 = ((t & 7) ^ (rr & 7)) << 3;   // pre-swizzled source column
  const int lbase = (t & 192) * 8;             // wave-uniform LDS dest base
  // stage Q (256 rows x 64 = 32KB) through the K-stage region
#pragma unroll
  for (int i = 0; i < 8; ++i)
    g2l16(&Qb[(size_t)(s0 + i * 32 + rr) * 2048 + co0], &SMEM[i * 2048 + lbase]);
  __syncthreads();
  bf16x8 qb[2][4];
#pragma unroll
  for (int qt = 0; qt < 2; ++qt)
#pragma unroll
    for (int ks = 0; ks < 4; ++ks)
      qb[qt][ks] = *(const bf16x8*)&SMEM[sw(w * 64 + qt * 32 + lh, ks * 16 + H * 8)];
  __syncthreads();
  // prologue DMA: stages 0,1,2 (4 loads each per thread -> 12 outstanding)
#pragma unroll
  for (int s = 0; s < 3; ++s)
#pragma unroll
    for (int i = 0; i < 2; ++i) {
      g2l16(&Kb[(size_t)(s * 64 + i * 32 + rr) * 2048 + co0],
            &SMEM[s * 4096 + i * 2048 + lbase]);
      g2l16(&Vtb[(size_t)(i * 32 + rr) * 2048 + s * 64 + co0],
            &SMEM[16384 + s * 4096 + i * 2048 + lbase]);
    }
  f32x16 o_acc[2][2] = {};
  float rsA[2] = {0.f, 0.f}, rsB[2] = {0.f, 0.f};
  for (int rd = 0; rd < 32; ++rd) {
    const int cur = rd & 3;
    const bf16* Ks = &SMEM[cur * 4096];
    const bf16* Vs = &SMEM[16384 + cur * 4096];
    // counted wait: stage rd landed; stages rd+1,rd+2 may stay in flight
    if (rd < 30)       asm volatile("s_waitcnt vmcnt(8)" ::: "memory");
    else if (rd == 30) asm volatile("s_waitcnt vmcnt(4)" ::: "memory");
    else               asm volatile("s_waitcnt vmcnt(0)" ::: "memory");
    __builtin_amdgcn_s_barrier();              // all waves: stage rd ready,
    __builtin_amdgcn_sched_barrier(0);         // slot (rd-1)&3 fully consumed
    if (rd <= 28) {
      int st = rd + 3, nb = st & 3, t0n = st * 64;
#pragma unroll
      for (int i = 0; i < 2; ++i) {
        g2l16(&Kb[(size_t)(t0n + i * 32 + rr) * 2048 + co0],
              &SMEM[nb * 4096 + i * 2048 + lbase]);
        g2l16(&Vtb[(size_t)(i * 32 + rr) * 2048 + t0n + co0],
              &SMEM[16384 + nb * 4096 + i * 2048 + lbase]);
      }
    }
#pragma unroll
    for (int tt = 0; tt < 2; ++tt) {
      // S^T tiles (t = tt*32.., s = w*64 + qt*32..): A=K[t][d], B=Q[s][d]
      bf16x8 kb[4];
#pragma unroll
      for (int ks = 0; ks < 4; ++ks)
        kb[ks] = *(const bf16x8*)&Ks[sw(tt * 32 + lh, ks * 16 + H * 8)];
      f32x16 sc[2] = {};
      __builtin_amdgcn_s_setprio(1);
#pragma unroll
      for (int ks = 0; ks < 4; ++ks)
#pragma unroll
        for (int qt = 0; qt < 2; ++qt)
          sc[qt] = __builtin_amdgcn_mfma_f32_32x32x16_bf16(kb[ks], qb[qt][ks], sc[qt], 0, 0, 0);
      __builtin_amdgcn_s_setprio(0);
      // exp2 + pack; reg r holds row t = (r&3)+8*(r>>2)+4H, col s=lh (per qt)
      u32 pk[2][8];
#pragma unroll
      for (int qt = 0; qt < 2; ++qt)
#pragma unroll
        for (int i = 0; i < 8; ++i) {
          float p0 = __builtin_amdgcn_exp2f(sc[qt][2 * i]);
          float p1 = __builtin_amdgcn_exp2f(sc[qt][2 * i + 1]);
          rsA[qt] += p0;
          rsB[qt] += p1;
          pk[qt][i] = pkbf(p0, p1);
        }
      // PV: A(m=s, k=t) assembled via cross-half permlane swaps (VALU, no LDS)
#pragma unroll
      for (int ks2 = 0; ks2 < 2; ++ks2) {
        bf16x8 pa[2];
#pragma unroll
        for (int qt = 0; qt < 2; ++qt) {
          u32x4 av;
#if __has_builtin(__builtin_amdgcn_permlane32_swap)
          i32x2 sA = __builtin_amdgcn_permlane32_swap(
              (int)pk[qt][ks2 * 4 + 0], (int)pk[qt][ks2 * 4 + 2], false, false);
          i32x2 sB = __builtin_amdgcn_permlane32_swap(
              (int)pk[qt][ks2 * 4 + 1], (int)pk[qt][ks2 * 4 + 3], false, false);
          av[0] = (u32)sA[0]; av[1] = (u32)sB[0]; av[2] = (u32)sA[1]; av[3] = (u32)sB[1];
#else
          u32 xx[4];
          xx[0] = __shfl_xor((int)pk[qt][ks2 * 4 + 0], 32);
          xx[1] = __shfl_xor((int)pk[qt][ks2 * 4 + 1], 32);
          xx[2] = __shfl_xor((int)pk[qt][ks2 * 4 + 2], 32);
          xx[3] = __shfl_xor((int)pk[qt][ks2 * 4 + 3], 32);
          av[0] = H ? xx[2] : pk[qt][ks2 * 4 + 0];
          av[1] = H ? xx[3] : pk[qt][ks2 * 4 + 1];
          av[2] = H ? pk[qt][ks2 * 4 + 2] : xx[0];
          av[3] = H ? pk[qt][ks2 * 4 + 3] : xx[1];
#endif
          pa[qt] = __builtin_bit_cast(bf16x8, av);
        }
        __builtin_amdgcn_s_setprio(1);
#pragma unroll
        for (int ht = 0; ht < 2; ++ht) {
          bf16x8 vb = *(const bf16x8*)&Vs[sw(ht * 32 + lh, tt * 32 + ks2 * 16 + H * 8)];
#pragma unroll
          for (int qt = 0; qt < 2; ++qt)
            o_acc[qt][ht] = __builtin_amdgcn_mfma_f32_32x32x16_bf16(pa[qt], vb, o_acc[qt][ht], 0, 0, 0);
        }
        __builtin_amdgcn_s_setprio(0);
      }
    }
  }
  // epilogue: complete denominators, normalize, store
#pragma unroll
  for (int qt = 0; qt < 2; ++qt) {
    float rs = rsA[qt] + rsB[qt];
    rs += __shfl_xor(rs, 32);
    float inv = 1.f / rs;
#pragma unroll
    for (int r = 0; r < 16; ++r) {
      int sl = (r & 3) + 8 * (r >> 2) + 4 * H;   // local s of this reg-row
      float invr = __shfl(inv, sl);
      size_t base = (size_t)(b * 2048 + s0 + w * 64 + qt * 32 + sl) * 1024 + n * 64;
#pragma unroll
      for (int ht = 0; ht < 2; ++ht)
        after[base + ht * 32 + lh] = (bf16)(o_acc[qt][ht][r] * invr);
    }
  }
}

// ---------------- launch ----------------
extern "C" void kernel_launch(void* const* d_in, const int* in_sizes, int n_in,
                              void* d_out, int out_size, void* d_ws, size_t ws_size,
                              hipStream_t stream) {
  const float* x  = (const float*)d_in[0];
  const float* Wq = (const float*)d_in[1];
  const float* bq = (const float*)d_in[2];
  const float* Wk = (const float*)d_in[3];
  const float* bk = (const float*)d_in[4];
  const float* Wv = (const float*)d_in[5];
  const float* bv = (const float*)d_in[6];
  const float* Wo = (const float*)d_in[7];
  const float* bo = (const float*)d_in[8];
  float* out = (float*)d_out;

  bf16* WT_all    = (bf16*)d_ws;                         // [3072 nh][1024 d]
  bf16* WoT       = WT_all + (size_t)3072 * 1024;        // [1024 d][1024 c]
  float* bias_all = (float*)(WoT + (size_t)1024 * 1024); // [3072]
  bf16* xb        = (bf16*)(bias_all + 4096);            // [8192][1024]
  bf16* QKb       = xb + (size_t)BS * Dd;                // [8192][2048] (Q|K)
  bf16* VTb       = QKb + (size_t)BS * 2048;             // [64 bn][64 h][2048 s]
  bf16* after     = VTb + (size_t)Bb * NH * HD * Ss;     // [8192][1024]

  prep<<<dim3(8192, 2), dim3(256), 0, stream>>>(x, xb, Wq, Wk, Wv, Wo, bq, bk, bv,
                                                WT_all, WoT, bias_all);
  gemm_qkv<<<dim3(1536), dim3(256), 0, stream>>>(xb, WT_all, bias_all, QKb, VTb);
  attn<<<dim3(512), dim3(256), 0, stream>>>(QKb, VTb, after);
  gemm_out<<<dim3(512), dim3(256), 0, stream>>>(after, WoT, bo, out);
}

// Round 3
// 264.943 us; speedup vs baseline: 1.0511x; 1.0511x over previous
//
#include <hip/hip_runtime.h>

typedef __bf16 bf16;
typedef bf16 bf16x8 __attribute__((ext_vector_type(8)));
typedef bf16 bf16x4 __attribute__((ext_vector_type(4)));
typedef bf16 bf16x2 __attribute__((ext_vector_type(2)));
typedef float f32x4 __attribute__((ext_vector_type(4)));
typedef float f32x16 __attribute__((ext_vector_type(16)));
typedef unsigned int u32;
typedef u32 u32x4 __attribute__((ext_vector_type(4)));
typedef int i32x2 __attribute__((ext_vector_type(2)));

constexpr int Bb = 4, Ss = 2048, Dd = 1024, NH = 16, HD = 64;
constexpr int BS = Bb * Ss;          // 8192
constexpr float CSC = 0.18033688011112042f;  // (1/sqrt(64)) * log2(e), folded into Wq

__device__ __forceinline__ int sw(int row, int col) {
  return (row << 6) + (col ^ ((row & 7) << 3));
}
__device__ __forceinline__ int sw128(int row, int col) {
  return (row << 7) + (col ^ ((row & 7) << 3));
}

__device__ __forceinline__ void g2l16(const bf16* g, bf16* l) {
  __builtin_amdgcn_global_load_lds(
      (const __attribute__((address_space(1))) void*)g,
      (__attribute__((address_space(3))) void*)l, 16, 0, 0);
}

__device__ __forceinline__ u32 pkbf(float a, float b) {
  bf16x2 v = {(bf16)a, (bf16)b};
  return __builtin_bit_cast(u32, v);
}

// ---------------- prep: x cvt + weight transposes + bias ----------------
__global__ void prep(const float* __restrict__ x, bf16* __restrict__ xb,
                     const float* __restrict__ Wq, const float* __restrict__ Wk,
                     const float* __restrict__ Wv, const float* __restrict__ Wo,
                     const float* __restrict__ bq, const float* __restrict__ bk,
                     const float* __restrict__ bv,
                     bf16* __restrict__ WT_all, bf16* __restrict__ WoT,
                     float* __restrict__ bias_all) {
  __shared__ bf16 Ts[64 * 72];
  const int t = threadIdx.x;
  if (blockIdx.y == 0) {           // x: f32 -> bf16 (8192 blocks)
    int o = (blockIdx.x * 256 + t) * 4;
    f32x4 v = *(const f32x4*)&x[o];
    bf16x4 r = {(bf16)v[0], (bf16)v[1], (bf16)v[2], (bf16)v[3]};
    *(bf16x4*)&xb[o] = r;
    return;
  }
  if (blockIdx.x > 1024) return;
  if (blockIdx.x == 1024) {
    for (int j = t; j < 3072; j += 256) {
      int s2 = j >> 10;
      const float* bb = (s2 == 0) ? bq : (s2 == 1) ? bk : bv;
      bias_all[j] = bb[j & 1023] * (s2 == 0 ? CSC : 1.0f);
    }
    return;
  }
  const int sel = blockIdx.x >> 8, bx = blockIdx.x & 255;
  if (sel < 3) {
    const float* W = (sel == 0) ? Wq : (sel == 1) ? Wk : Wv;
    float scale = (sel == 0) ? CSC : 1.0f;
    int head = bx >> 4, dt = bx & 15;
    const float* src = W + head * 65536 + dt * 64 * 64;   // [64 d][64 h]
#pragma unroll
    for (int i = 0; i < 4; ++i) {
      int idx = i * 256 + t;
      int dr = idx >> 4, hc = (idx & 15) * 4;
      f32x4 v = *(const f32x4*)&src[dr * 64 + hc];
#pragma unroll
      for (int k = 0; k < 4; ++k) Ts[(hc + k) * 72 + dr] = (bf16)(v[k] * scale);
    }
    __syncthreads();
    bf16* dst = WT_all + (size_t)sel * 1048576 + (size_t)(head * 64) * 1024 + dt * 64;
#pragma unroll
    for (int i = 0; i < 2; ++i) {
      int idx = i * 256 + t;
      int hr = idx >> 3, ch = (idx & 7) * 8;
      *(bf16x8*)&dst[(size_t)hr * 1024 + ch] = *(const bf16x8*)&Ts[hr * 72 + ch];
    }
  } else {
    int ct = bx >> 4, dt = bx & 15;
    const float* src = Wo + (size_t)(ct * 64) * 1024 + dt * 64;
#pragma unroll
    for (int i = 0; i < 4; ++i) {
      int idx = i * 256 + t;
      int cr = idx >> 4, dc = (idx & 15) * 4;
      f32x4 v = *(const f32x4*)&src[(size_t)cr * 1024 + dc];
#pragma unroll
      for (int k = 0; k < 4; ++k) Ts[(dc + k) * 72 + cr] = (bf16)v[k];
    }
    __syncthreads();
    bf16* dst = WoT + (size_t)(dt * 64) * 1024 + ct * 64;
#pragma unroll
    for (int i = 0; i < 2; ++i) {
      int idx = i * 256 + t;
      int dr = idx >> 3, ch = (idx & 7) * 8;
      *(bf16x8*)&dst[(size_t)dr * 1024 + ch] = *(const bf16x8*)&Ts[dr * 72 + ch];
    }
  }
}

// ---------------- shared 128x128 K=1024 MFMA core (legacy path) ----------------
__device__ __forceinline__ void gemm_core(const bf16* __restrict__ A,
                                          const bf16* __restrict__ BT,
                                          int m0, int n0, bf16* As, bf16* Bs,
                                          f32x4 (&acc)[4][4]) {
  const int t = threadIdx.x;
  const int l = t & 63, q = l >> 4, lm = l & 15;
  const int w = t >> 6, wm = w & 1, wn = w >> 1;
  int ro[4], co[4];
#pragma unroll
  for (int i = 0; i < 4; ++i) {
    int o = i * 256 + t;
    ro[i] = o >> 3;
    co[i] = ((o & 7) ^ ((o >> 3) & 7)) << 3;
  }
  const int lbase = (t & 192) * 8;
  for (int k0 = 0; k0 < 1024; k0 += 64) {
    __syncthreads();
#pragma unroll
    for (int i = 0; i < 4; ++i)
      g2l16(&A[(size_t)(m0 + ro[i]) * 1024 + k0 + co[i]], &As[i * 2048 + lbase]);
#pragma unroll
    for (int i = 0; i < 4; ++i)
      g2l16(&BT[(size_t)(n0 + ro[i]) * 1024 + k0 + co[i]], &Bs[i * 2048 + lbase]);
    __syncthreads();
#pragma unroll
    for (int kh = 0; kh < 2; ++kh) {
      bf16x8 a[4], b[4];
#pragma unroll
      for (int i = 0; i < 4; ++i)
        a[i] = *(const bf16x8*)&As[sw(wm * 64 + i * 16 + lm, kh * 32 + q * 8)];
#pragma unroll
      for (int i = 0; i < 4; ++i)
        b[i] = *(const bf16x8*)&Bs[sw(wn * 64 + i * 16 + lm, kh * 32 + q * 8)];
#pragma unroll
      for (int mt = 0; mt < 4; ++mt)
#pragma unroll
        for (int nt = 0; nt < 4; ++nt)
          acc[mt][nt] = __builtin_amdgcn_mfma_f32_16x16x32_bf16(a[mt], b[nt], acc[mt][nt], 0, 0, 0);
    }
  }
}

// ---------------- QK projection: 256x256 8-wave 4-phase pipelined GEMM ----------
// C[8192,2048] = xb * WT^T (+bias). 256 blocks = 1/CU. 512 thr = 8 waves (2Mx4N),
// per-wave 128x64 out. LDS 128KB: 2 buf x (A 32KB + B 32KB), BK=64.
// Per K-tile: 4 phases {ds_read subtile | stage half-tile -> barrier -> 16 MFMA
// -> barrier}; ONE counted vmcnt(4) per K-tile (never 0 in loop).
// LDS row order is permuted so each half-tile is read in exactly one phase:
//   A-half h holds tile-rows {h*64..h*64+63} U {128+h*64..}, B-half h the
//   analogous 32-row groups; g2l16's per-lane global source implements the
//   permutation + sw() XOR pre-swizzle (LDS dest stays linear).
__global__ __launch_bounds__(512, 2) void gemm_qk8(const bf16* __restrict__ A,
                                                   const bf16* __restrict__ BT,
                                                   const float* __restrict__ bias_all,
                                                   bf16* __restrict__ C) {
  __shared__ __align__(16) bf16 SMEM[65536];   // 128 KiB
  const int t = threadIdx.x;
  const int l = t & 63, q = l >> 4, lm = l & 15;
  const int w = t >> 6, wm = w & 1, wn = w >> 1;
  const int bid = blockIdx.x;
  const int xcd = bid & 7, cc = bid >> 3;       // 32 blocks per XCD chunk
  const int mt = xcd * 4 + (cc >> 3), nt = cc & 7;
  const int m0 = mt * 256, n0 = nt * 256;
  const bf16* Ag = A + (size_t)m0 * 1024;
  const bf16* Bg = BT + (size_t)n0 * 1024;
  const int sR = t >> 3;                        // 0..63
  const int sC = t & 7;                         // 16B col group
  const int dstb = (t & 448) * 8;               // wave-uniform dest base (w*512)

  auto stA = [&](int bufb, int h, int kt) {     // one A half-tile (2 x g2l16)
#pragma unroll
    for (int i = 0; i < 2; ++i) {
      int Lh = i * 64 + sR;                     // LDS row within half
      int gr = ((Lh >> 6) << 7) + h * 64 + (Lh & 63);   // permuted global row
      g2l16(&Ag[(size_t)gr * 1024 + kt * 64 + ((sC ^ (Lh & 7)) << 3)],
            &SMEM[bufb * 32768 + h * 8192 + i * 4096 + dstb]);
    }
  };
  auto stB = [&](int bufb, int h, int kt) {
#pragma unroll
    for (int i = 0; i < 2; ++i) {
      int Lh = i * 64 + sR;
      int gr = ((Lh >> 5) << 6) + h * 32 + (Lh & 31);
      g2l16(&Bg[(size_t)gr * 1024 + kt * 64 + ((sC ^ (Lh & 7)) << 3)],
            &SMEM[bufb * 32768 + 16384 + h * 8192 + i * 4096 + dstb]);
    }
  };
  auto rdA = [&](int base, int mt16, int ks) {
    int L = ((mt16 >> 2) << 7) + wm * 64 + ((mt16 & 3) << 4) + lm;
    return *(const bf16x8*)&SMEM[base + sw(L, ks * 32 + q * 8)];
  };
  auto rdB = [&](int base, int nt16, int ks) {
    int L = ((nt16 >> 1) << 7) + wn * 32 + ((nt16 & 1) << 4) + lm;
    return *(const bf16x8*)&SMEM[base + 16384 + sw(L, ks * 32 + q * 8)];
  };

  // prologue: tile0 full -> buf0; tile1 A-half0/B-half0 -> buf1 (A1/B1 come in j0)
  stA(0, 0, 0); stA(0, 1, 0); stB(0, 0, 0); stB(0, 1, 0);
  stA(1, 0, 1); stB(1, 0, 1);
  asm volatile("s_waitcnt vmcnt(4)" ::: "memory");   // tile0 landed
  __builtin_amdgcn_s_barrier();
  __builtin_amdgcn_sched_barrier(0);

  f32x4 acc[8][4] = {};
  int cur = 0;
  for (int kt = 0; kt < 16; ++kt, cur ^= 1) {
    const int base = cur * 32768;
    bf16x8 af[4][2], b0[2][2], b1[2][2];
    // ---- phase 0: quadrant (m-half0, n-half0) ----
#pragma unroll
    for (int mi = 0; mi < 4; ++mi)
#pragma unroll
      for (int ks = 0; ks < 2; ++ks) af[mi][ks] = rdA(base, mi, ks);
#pragma unroll
    for (int ni = 0; ni < 2; ++ni)
#pragma unroll
      for (int ks = 0; ks < 2; ++ks) b0[ni][ks] = rdB(base, ni, ks);
    if (kt + 1 < 16) { stA(cur ^ 1, 1, kt + 1); stB(cur ^ 1, 1, kt + 1); }
    __builtin_amdgcn_s_barrier();
    __builtin_amdgcn_s_setprio(1);
#pragma unroll
    for (int mi = 0; mi < 4; ++mi)
#pragma unroll
      for (int ni = 0; ni < 2; ++ni)
#pragma unroll
        for (int ks = 0; ks < 2; ++ks)
          acc[mi][ni] = __builtin_amdgcn_mfma_f32_16x16x32_bf16(af[mi][ks], b0[ni][ks], acc[mi][ni], 0, 0, 0);
    __builtin_amdgcn_s_setprio(0);
    __builtin_amdgcn_sched_barrier(0);
    __builtin_amdgcn_s_barrier();
    __builtin_amdgcn_sched_barrier(0);
    // ---- phase 1: (m-half0, n-half1) ----
#pragma unroll
    for (int ni = 0; ni < 2; ++ni)
#pragma unroll
      for (int ks = 0; ks < 2; ++ks) b1[ni][ks] = rdB(base, 2 + ni, ks);
    __builtin_amdgcn_s_barrier();
    __builtin_amdgcn_s_setprio(1);
#pragma unroll
    for (int mi = 0; mi < 4; ++mi)
#pragma unroll
      for (int ni = 0; ni < 2; ++ni)
#pragma unroll
        for (int ks = 0; ks < 2; ++ks)
          acc[mi][2 + ni] = __builtin_amdgcn_mfma_f32_16x16x32_bf16(af[mi][ks], b1[ni][ks], acc[mi][2 + ni], 0, 0, 0);
    __builtin_amdgcn_s_setprio(0);
    __builtin_amdgcn_sched_barrier(0);
    __builtin_amdgcn_s_barrier();
    __builtin_amdgcn_sched_barrier(0);
    // ---- phase 2: (m-half1, n-half0) ----
#pragma unroll
    for (int mi = 0; mi < 4; ++mi)
#pragma unroll
      for (int ks = 0; ks < 2; ++ks) af[mi][ks] = rdA(base, 4 + mi, ks);
#pragma unroll
    for (int ni = 0; ni < 2; ++ni)
#pragma unroll
      for (int ks = 0; ks < 2; ++ks) b0[ni][ks] = rdB(base, ni, ks);
    if (kt + 2 < 16) stA(cur, 0, kt + 2);        // A-half0 freed after phase 0
    __builtin_amdgcn_s_barrier();
    __builtin_amdgcn_s_setprio(1);
#pragma unroll
    for (int mi = 0; mi < 4; ++mi)
#pragma unroll
      for (int ni = 0; ni < 2; ++ni)
#pragma unroll
        for (int ks = 0; ks < 2; ++ks)
          acc[4 + mi][ni] = __builtin_amdgcn_mfma_f32_16x16x32_bf16(af[mi][ks], b0[ni][ks], acc[4 + mi][ni], 0, 0, 0);
    __builtin_amdgcn_s_setprio(0);
    __builtin_amdgcn_sched_barrier(0);
    __builtin_amdgcn_s_barrier();
    __builtin_amdgcn_sched_barrier(0);
    // ---- phase 3: (m-half1, n-half1) ----
#pragma unroll
    for (int ni = 0; ni < 2; ++ni)
#pragma unroll
      for (int ks = 0; ks < 2; ++ks) b1[ni][ks] = rdB(base, 2 + ni, ks);
    if (kt + 2 < 16) stB(cur, 0, kt + 2);        // B-half0 freed after phase 2
    __builtin_amdgcn_s_barrier();
    __builtin_amdgcn_s_setprio(1);
#pragma unroll
    for (int mi = 0; mi < 4; ++mi)
#pragma unroll
      for (int ni = 0; ni < 2; ++ni)
#pragma unroll
        for (int ks = 0; ks < 2; ++ks)
          acc[4 + mi][2 + ni] = __builtin_amdgcn_mfma_f32_16x16x32_bf16(af[mi][ks], b1[ni][ks], acc[4 + mi][2 + ni], 0, 0, 0);
    __builtin_amdgcn_s_setprio(0);
    // counted guard: all but the 4 newest loads (this group's ph2/ph3 stages)
    // have landed => next tile fully staged before its phase-0 reads.
    asm volatile("s_waitcnt vmcnt(4)" ::: "memory");
    __builtin_amdgcn_sched_barrier(0);
    __builtin_amdgcn_s_barrier();
    __builtin_amdgcn_sched_barrier(0);
  }
  // epilogue: bias + store
#pragma unroll
  for (int mi = 0; mi < 8; ++mi) {
    int row = m0 + wm * 128 + mi * 16 + q * 4;
#pragma unroll
    for (int ni = 0; ni < 4; ++ni) {
      int col = n0 + wn * 64 + ni * 16 + lm;
      float bb = bias_all[col];
#pragma unroll
      for (int r = 0; r < 4; ++r)
        C[(size_t)(row + r) * 2048 + col] = (bf16)(acc[mi][ni][r] + bb);
    }
  }
}

// ---------------- V projection GEMM (512 blocks, legacy core) ----------------
__global__ __launch_bounds__(256) void gemm_v(const bf16* __restrict__ xb,
                                              const bf16* __restrict__ WT,
                                              const float* __restrict__ bias_all,
                                              bf16* __restrict__ VTb) {
  __shared__ __align__(16) bf16 SMEM[2 * 128 * 64];
  bf16* As = SMEM;
  bf16* Bs = SMEM + 128 * 64;
  const int bid = blockIdx.x;
  const int t = threadIdx.x;
  const int l = t & 63, q = l >> 4, lm = l & 15;
  const int w = t >> 6, wm = w & 1, wn = w >> 1;
  const int xcd = bid & 7, idx = bid >> 3;
  const int m0 = (idx >> 3) * 128;
  const int n0 = (xcd * 8 + (idx & 7)) * 128;
  const bf16* A = WT + (size_t)2048 * 1024;   // Wv^T [1024 nh][1024 d]
  const bf16* BT = xb;
  f32x4 acc[4][4] = {};
  gemm_core(A, BT, m0, n0, As, Bs, acc);
  // stage C-tile (m=nh 128, n=s 128) in LDS, then write coalesced VT rows
  __syncthreads();
#pragma unroll
  for (int nt = 0; nt < 4; ++nt) {
    int sl = wn * 64 + nt * 16 + lm;
#pragma unroll
    for (int mt = 0; mt < 4; ++mt) {
      int ml = wm * 64 + mt * 16 + q * 4;
#pragma unroll
      for (int r = 0; r < 4; ++r)
        SMEM[sw128(ml + r, sl)] = (bf16)(acc[mt][nt][r] + bias_all[2048 + m0 + ml + r]);
    }
  }
  __syncthreads();
  int hh = t >> 1, half = (t & 1) * 64;
  int m = m0 + hh;
  size_t gb = (size_t)((n0 >> 11) * 16 + (m >> 6)) * 131072 +
              (size_t)(m & 63) * 2048 + (n0 & 2047) + half;
#pragma unroll
  for (int k = 0; k < 8; ++k)
    *(bf16x8*)&VTb[gb + k * 8] = *(const bf16x8*)&SMEM[sw128(hh, half + k * 8)];
}

// ---------------- out-proj GEMM (512 blocks, f32 out) ----------------
__global__ __launch_bounds__(256) void gemm_out(const bf16* __restrict__ after,
                                                const bf16* __restrict__ WoT,
                                                const float* __restrict__ bo,
                                                float* __restrict__ out) {
  __shared__ __align__(16) bf16 SMEM[2 * 128 * 64];
  const int bid = blockIdx.x;
  const int t = threadIdx.x;
  const int l = t & 63, q = l >> 4, lm = l & 15;
  const int w = t >> 6, wm = w & 1, wn = w >> 1;
  const int xcd = bid & 7, idx = bid >> 3;
  const int n0 = xcd * 128, m0 = idx * 128;
  f32x4 acc[4][4] = {};
  gemm_core(after, WoT, m0, n0, SMEM, SMEM + 128 * 64, acc);
#pragma unroll
  for (int nt = 0; nt < 4; ++nt) {
    int col = n0 + wn * 64 + nt * 16 + lm;
    float bb = bo[col];
#pragma unroll
    for (int mt = 0; mt < 4; ++mt) {
      int row = m0 + wm * 64 + mt * 16 + q * 4;
#pragma unroll
      for (int r = 0; r < 4; ++r)
        out[(size_t)(row + r) * 1024 + col] = acc[mt][nt][r] + bb;
    }
  }
}

// ---------------- flash attention: 32x32 MFMA, 64 Q-rows/wave ----------------
__global__ __launch_bounds__(256, 2) void attn(const bf16* __restrict__ QK,
                                               const bf16* __restrict__ VT,
                                               bf16* __restrict__ after) {
  // 64KB: K stages [4][4096] at 0, V stages [4][4096] at 16384 (elements).
  __shared__ __align__(16) bf16 SMEM[32768];
  const int t = threadIdx.x;
  const int l = t & 63, w = t >> 6;
  const int lh = l & 31, H = l >> 5;          // half-wave id
  const int f = blockIdx.x;
  const int bn = (f & 7) | ((f >> 6) << 3);   // XCD keeps one bn-group's K/V in L2
  const int s0 = ((f >> 3) & 7) * 256;
  const int b = bn >> 4, n = bn & 15;
  const bf16* Qb = QK + (size_t)(b * 2048) * 2048 + n * 64;
  const bf16* Kb = Qb + 1024;
  const bf16* Vtb = VT + (size_t)bn * 131072;
  const int rr = t >> 3;                       // row-in-32 per staging iter
  const int co0 = ((t & 7) ^ (rr & 7)) << 3;   // pre-swizzled source column
  const int lbase = (t & 192) * 8;             // wave-uniform LDS dest base
  // stage Q (256 rows x 64 = 32KB) through the K-stage region
#pragma unroll
  for (int i = 0; i < 8; ++i)
    g2l16(&Qb[(size_t)(s0 + i * 32 + rr) * 2048 + co0], &SMEM[i * 2048 + lbase]);
  __syncthreads();
  bf16x8 qb[2][4];
#pragma unroll
  for (int qt = 0; qt < 2; ++qt)
#pragma unroll
    for (int ks = 0; ks < 4; ++ks)
      qb[qt][ks] = *(const bf16x8*)&SMEM[sw(w * 64 + qt * 32 + lh, ks * 16 + H * 8)];
  __syncthreads();
  // prologue DMA: stages 0,1,2
#pragma unroll
  for (int s = 0; s < 3; ++s)
#pragma unroll
    for (int i = 0; i < 2; ++i) {
      g2l16(&Kb[(size_t)(s * 64 + i * 32 + rr) * 2048 + co0],
            &SMEM[s * 4096 + i * 2048 + lbase]);
      g2l16(&Vtb[(size_t)(i * 32 + rr) * 2048 + s * 64 + co0],
            &SMEM[16384 + s * 4096 + i * 2048 + lbase]);
    }
  f32x16 o_acc[2][2] = {};
  float rsA[2] = {0.f, 0.f}, rsB[2] = {0.f, 0.f};
  for (int rd = 0; rd < 32; ++rd) {
    const int cur = rd & 3;
    const bf16* Ks = &SMEM[cur * 4096];
    const bf16* Vs = &SMEM[16384 + cur * 4096];
    if (rd < 30)       asm volatile("s_waitcnt vmcnt(8)" ::: "memory");
    else if (rd == 30) asm volatile("s_waitcnt vmcnt(4)" ::: "memory");
    else               asm volatile("s_waitcnt vmcnt(0)" ::: "memory");
    __builtin_amdgcn_s_barrier();
    __builtin_amdgcn_sched_barrier(0);
    if (rd <= 28) {
      int st = rd + 3, nb = st & 3, t0n = st * 64;
#pragma unroll
      for (int i = 0; i < 2; ++i) {
        g2l16(&Kb[(size_t)(t0n + i * 32 + rr) * 2048 + co0],
              &SMEM[nb * 4096 + i * 2048 + lbase]);
        g2l16(&Vtb[(size_t)(i * 32 + rr) * 2048 + t0n + co0],
              &SMEM[16384 + nb * 4096 + i * 2048 + lbase]);
      }
    }
#pragma unroll
    for (int tt = 0; tt < 2; ++tt) {
      bf16x8 kb[4];
#pragma unroll
      for (int ks = 0; ks < 4; ++ks)
        kb[ks] = *(const bf16x8*)&Ks[sw(tt * 32 + lh, ks * 16 + H * 8)];
      f32x16 sc[2] = {};
      __builtin_amdgcn_s_setprio(1);
#pragma unroll
      for (int ks = 0; ks < 4; ++ks)
#pragma unroll
        for (int qt = 0; qt < 2; ++qt)
          sc[qt] = __builtin_amdgcn_mfma_f32_32x32x16_bf16(kb[ks], qb[qt][ks], sc[qt], 0, 0, 0);
      __builtin_amdgcn_s_setprio(0);
      u32 pk[2][8];
#pragma unroll
      for (int qt = 0; qt < 2; ++qt)
#pragma unroll
        for (int i = 0; i < 8; ++i) {
          float p0 = __builtin_amdgcn_exp2f(sc[qt][2 * i]);
          float p1 = __builtin_amdgcn_exp2f(sc[qt][2 * i + 1]);
          rsA[qt] += p0;
          rsB[qt] += p1;
          pk[qt][i] = pkbf(p0, p1);
        }
#pragma unroll
      for (int ks2 = 0; ks2 < 2; ++ks2) {
        bf16x8 pa[2];
#pragma unroll
        for (int qt = 0; qt < 2; ++qt) {
          u32x4 av;
#if __has_builtin(__builtin_amdgcn_permlane32_swap)
          i32x2 sA = __builtin_amdgcn_permlane32_swap(
              (int)pk[qt][ks2 * 4 + 0], (int)pk[qt][ks2 * 4 + 2], false, false);
          i32x2 sB = __builtin_amdgcn_permlane32_swap(
              (int)pk[qt][ks2 * 4 + 1], (int)pk[qt][ks2 * 4 + 3], false, false);
          av[0] = (u32)sA[0]; av[1] = (u32)sB[0]; av[2] = (u32)sA[1]; av[3] = (u32)sB[1];
#else
          u32 xx[4];
          xx[0] = __shfl_xor((int)pk[qt][ks2 * 4 + 0], 32);
          xx[1] = __shfl_xor((int)pk[qt][ks2 * 4 + 1], 32);
          xx[2] = __shfl_xor((int)pk[qt][ks2 * 4 + 2], 32);
          xx[3] = __shfl_xor((int)pk[qt][ks2 * 4 + 3], 32);
          av[0] = H ? xx[2] : pk[qt][ks2 * 4 + 0];
          av[1] = H ? xx[3] : pk[qt][ks2 * 4 + 1];
          av[2] = H ? pk[qt][ks2 * 4 + 2] : xx[0];
          av[3] = H ? pk[qt][ks2 * 4 + 3] : xx[1];
#endif
          pa[qt] = __builtin_bit_cast(bf16x8, av);
        }
        __builtin_amdgcn_s_setprio(1);
#pragma unroll
        for (int ht = 0; ht < 2; ++ht) {
          bf16x8 vb = *(const bf16x8*)&Vs[sw(ht * 32 + lh, tt * 32 + ks2 * 16 + H * 8)];
#pragma unroll
          for (int qt = 0; qt < 2; ++qt)
            o_acc[qt][ht] = __builtin_amdgcn_mfma_f32_32x32x16_bf16(pa[qt], vb, o_acc[qt][ht], 0, 0, 0);
        }
        __builtin_amdgcn_s_setprio(0);
      }
    }
  }
#pragma unroll
  for (int qt = 0; qt < 2; ++qt) {
    float rs = rsA[qt] + rsB[qt];
    rs += __shfl_xor(rs, 32);
    float inv = 1.f / rs;
#pragma unroll
    for (int r = 0; r < 16; ++r) {
      int sl = (r & 3) + 8 * (r >> 2) + 4 * H;
      float invr = __shfl(inv, sl);
      size_t base = (size_t)(b * 2048 + s0 + w * 64 + qt * 32 + sl) * 1024 + n * 64;
#pragma unroll
      for (int ht = 0; ht < 2; ++ht)
        after[base + ht * 32 + lh] = (bf16)(o_acc[qt][ht][r] * invr);
    }
  }
}

// ---------------- launch ----------------
extern "C" void kernel_launch(void* const* d_in, const int* in_sizes, int n_in,
                              void* d_out, int out_size, void* d_ws, size_t ws_size,
                              hipStream_t stream) {
  const float* x  = (const float*)d_in[0];
  const float* Wq = (const float*)d_in[1];
  const float* bq = (const float*)d_in[2];
  const float* Wk = (const float*)d_in[3];
  const float* bk = (const float*)d_in[4];
  const float* Wv = (const float*)d_in[5];
  const float* bv = (const float*)d_in[6];
  const float* Wo = (const float*)d_in[7];
  const float* bo = (const float*)d_in[8];
  float* out = (float*)d_out;

  bf16* WT_all    = (bf16*)d_ws;                         // [3072 nh][1024 d]
  bf16* WoT       = WT_all + (size_t)3072 * 1024;        // [1024 d][1024 c]
  float* bias_all = (float*)(WoT + (size_t)1024 * 1024); // [3072]
  bf16* xb        = (bf16*)(bias_all + 4096);            // [8192][1024]
  bf16* QKb       = xb + (size_t)BS * Dd;                // [8192][2048] (Q|K)
  bf16* VTb       = QKb + (size_t)BS * 2048;             // [64 bn][64 h][2048 s]
  bf16* after     = VTb + (size_t)Bb * NH * HD * Ss;     // [8192][1024]

  prep<<<dim3(8192, 2), dim3(256), 0, stream>>>(x, xb, Wq, Wk, Wv, Wo, bq, bk, bv,
                                                WT_all, WoT, bias_all);
  gemm_qk8<<<dim3(256), dim3(512), 0, stream>>>(xb, WT_all, bias_all, QKb);
  gemm_v<<<dim3(512), dim3(256), 0, stream>>>(xb, WT_all, bias_all, VTb);
  attn<<<dim3(512), dim3(256), 0, stream>>>(QKb, VTb, after);
  gemm_out<<<dim3(512), dim3(256), 0, stream>>>(after, WoT, bo, out);
}